// Round 1
// baseline (315.886 us; speedup 1.0000x reference)
//
#include <hip/hip_runtime.h>
#include <math.h>

// Problem constants (fixed shapes for JointDecoder_57698590654834)
//   depth_logits: (B=2, D=128, H=256, W=256) f32
//   bev_logits:   (B=2, 2, 128, 128) f32
//   inv_K:        (B=2, 4, 4) f32
//   out:          (B, H, W, D, 3) f32
#define DD    128
#define HH    256
#define WW    256
#define BEVN  16384      // 128*128
#define LOG3  (-1.0986f)

// ---------------- Kernel A: log class-prob table ----------------
__global__ void jd_logcp_kernel(const float* __restrict__ bev,
                                float* __restrict__ logcp, int B) {
    int i = blockIdx.x * blockDim.x + threadIdx.x;
    if (i >= B * BEVN) return;
    int b  = i >> 14;
    int zx = i & (BEVN - 1);
    float x0 = bev[(b * 2 + 0) * BEVN + zx];
    float x1 = bev[(b * 2 + 1) * BEVN + zx];
    const float LO = 1e-7f;
    const float HI = (float)(1.0 - 1e-7);   // matches np: clip hi computed in f64 then cast
    float p0 = fminf(fmaxf(1.0f / (1.0f + expf(-x0)), LO), HI);
    float p1 = fminf(fmaxf(1.0f / (1.0f + expf(-x1)), LO), HI);
    float c0 = 1.0f - p1;
    float c1 = p1 * p0;
    float c2 = p1 * (1.0f - p0);
    float* o = logcp + (size_t)b * (3 * BEVN) + zx;
    o[0]         = logf(c0);
    o[BEVN]      = logf(c1);
    o[2 * BEVN]  = logf(c2);
}

// ---------------- Kernel B: softmax + lift + combine ----------------
// grid: B * H * (W/64) blocks of 256 threads. Block handles (b, h, 64 w's, all d).
__global__ __launch_bounds__(256) void jd_main_kernel(
        const float* __restrict__ depth, const float* __restrict__ invK,
        const float* __restrict__ logcp, float* __restrict__ out) {
    __shared__ float tile[DD * 65];   // tile[d*65 + w], +1 pad -> bank (d+w)%32 (2-way, free)
    __shared__ float pmax[4 * 64];
    __shared__ float psum[4 * 64];

    const int t    = threadIdx.x;
    const int lane = t & 63;
    const int q    = t >> 6;          // wave id 0..3
    const int bid  = blockIdx.x;
    const int w0   = (bid & 3) * 64;
    const int h    = (bid >> 2) & (HH - 1);
    const int b    = bid >> 10;

    // ---- Phase 1: log_softmax over d for 64 pixels (w = lane) ----
    const float* dp = depth + ((size_t)b * DD) * (HH * WW) + (size_t)h * WW + w0 + lane;
    const int dbase = q * 32;
    float v[32];
    float m = -INFINITY;
#pragma unroll
    for (int i = 0; i < 32; ++i) {
        v[i] = dp[(size_t)(dbase + i) * (HH * WW)];   // coalesced: 64 consecutive floats/wave
        m = fmaxf(m, v[i]);
    }
    pmax[q * 64 + lane] = m;
    __syncthreads();
    float mm = fmaxf(fmaxf(pmax[lane], pmax[64 + lane]),
                     fmaxf(pmax[128 + lane], pmax[192 + lane]));
    float s = 0.0f;
#pragma unroll
    for (int i = 0; i < 32; ++i) s += expf(v[i] - mm);
    psum[q * 64 + lane] = s;
    __syncthreads();
    float S  = ((psum[lane] + psum[64 + lane]) + psum[128 + lane]) + psum[192 + lane];
    float lS = logf(S);
#pragma unroll
    for (int i = 0; i < 32; ++i)
        tile[(dbase + i) * 65 + lane] = (v[i] - mm) - lS;   // final depth log-prob
    __syncthreads();

    // ---- Phase 2: lift + combine. lane <-> d, wave-uniform w ----
    const float* ik = invK + b * 16;
    const float ik00 = ik[0], ik01 = ik[1], ik02 = ik[2];
    const float ik10 = ik[4], ik11 = ik[5], ik12 = ik[6];
    const float ik20 = ik[8], ik21 = ik[9], ik22 = ik[10];

    // np.linspace(MIN_DEPTH, MAX_DEPTH, 128) in f64, endpoint pinned, cast f32
    const double stepd = (3.2875 - 0.1125) / 127.0;
    const int dA = lane, dB = lane + 64;
    const float dvA = (dA == 127) ? (float)3.2875 : (float)((double)dA * stepd + 0.1125);
    const float dvB = (dB == 127) ? (float)3.2875 : (float)((double)dB * stepd + 0.1125);

    const float* cp = logcp + (size_t)b * (3 * BEVN);
    const size_t pixbase0 = ((size_t)b * (HH * WW) + (size_t)h * WW + w0) * (DD * 3);
    const float yf = (float)h;

    for (int wi = 0; wi < 16; ++wi) {
        const int w = wi * 4 + q;
        const float xf = (float)(w0 + w);
        // einsum order: (ik_i0*x + ik_i1*y) + ik_i2, no FMA contraction
        const float camx = __fadd_rn(__fadd_rn(__fmul_rn(ik00, xf), __fmul_rn(ik01, yf)), ik02);
        const float camy = __fadd_rn(__fadd_rn(__fmul_rn(ik10, xf), __fmul_rn(ik11, yf)), ik12);
        const float camz = __fadd_rn(__fadd_rn(__fmul_rn(ik20, xf), __fmul_rn(ik21, yf)), ik22);
        float* op = out + pixbase0 + (size_t)w * (DD * 3);
#pragma unroll
        for (int half = 0; half < 2; ++half) {
            const int d = half * 64 + lane;
            const float dval = half ? dvB : dvA;
            const float dlp = tile[d * 65 + w];
            // pts = dval * cam, then * [1,-1,-1]
            float px = __fmul_rn(dval, camx);
            float py = __fmul_rn(dval, camy);
            float pz = __fmul_rn(dval, camz);
            py = -py; pz = -pz;
            // vox = trunc((pts - CAM_OFFSET) / RES), CAM_OFFSET = [-1.6, 0, -3.3]
            const float tx = __fsub_rn(px, -1.6f);
            const float ty = __fsub_rn(py, 0.0f);
            const float tz = __fsub_rn(pz, -3.3f);
            const int vx = (int)__fdiv_rn(tx, 0.025f);
            const int vy = (int)__fdiv_rn(ty, 0.025f);
            const int vz = (int)__fdiv_rn(tz, 0.025f);
            const bool valid = (vx >= 0) & (vx < 128) & (vz >= 0) & (vz < 128) & (vy <= 0);
            const int base = valid ? (vz * 128 + vx) : 0;   // safe_base, no divergence
            const float l0 = cp[base];
            const float l1 = cp[base + BEVN];
            const float l2 = cp[base + 2 * BEVN];
            const float e0 = __fadd_rn(valid ? l0 : LOG3, dlp);
            const float e1 = __fadd_rn(valid ? l1 : LOG3, dlp);
            const float e2 = __fadd_rn(valid ? l2 : LOG3, dlp);
            op[d * 3 + 0] = e0;
            op[d * 3 + 1] = e1;
            op[d * 3 + 2] = e2;
        }
    }
}

extern "C" void kernel_launch(void* const* d_in, const int* in_sizes, int n_in,
                              void* d_out, int out_size, void* d_ws, size_t ws_size,
                              hipStream_t stream) {
    const float* depth = (const float*)d_in[0];
    const float* bev   = (const float*)d_in[1];
    const float* invK  = (const float*)d_in[2];
    float* out = (float*)d_out;
    float* logcp = (float*)d_ws;   // B*3*16384 floats = 384 KB

    const int B = in_sizes[0] / (DD * HH * WW);   // = 2

    jd_logcp_kernel<<<(B * BEVN + 255) / 256, 256, 0, stream>>>(bev, logcp, B);
    jd_main_kernel<<<B * HH * (WW / 64), 256, 0, stream>>>(depth, invK, logcp, out);
}